// Round 4
// baseline (264.136 us; speedup 1.0000x reference)
//
#include <hip/hip_runtime.h>
#include <math.h>

#define D 128

typedef __attribute__((ext_vector_type(8))) short short8;
typedef __attribute__((ext_vector_type(4))) float f32x4;

__device__ __forceinline__ ushort f2bf(float f) {
    uint u = __float_as_uint(f);
    u += 0x7FFFu + ((u >> 16) & 1u);       // round-to-nearest-even
    return (ushort)(u >> 16);
}
__device__ __forceinline__ float bf2f(ushort h) { return __uint_as_float(((uint)h) << 16); }
__device__ __forceinline__ float lo2f(uint u) { return __uint_as_float(u << 16); }
__device__ __forceinline__ float hi2f(uint u) { return __uint_as_float(u & 0xFFFF0000u); }

// ---------------------------------------------------------------------------
// Convert x (N*128) and the 4 weight matrices (4*128*128) to bf16,
// and zero the counts array (fused, capture-safe).
// ---------------------------------------------------------------------------
__global__ void convert_kernel(
    const float* __restrict__ x,
    const float* __restrict__ Wq, const float* __restrict__ Wk,
    const float* __restrict__ Wv, const float* __restrict__ Ws,
    ushort* __restrict__ xb, ushort* __restrict__ wb,
    int* __restrict__ counts, int nx4, int N)
{
    int i = blockIdx.x * 256 + threadIdx.x;
    if (i < nx4) {
        float4 f = ((const float4*)x)[i];
        ushort4 h;
        h.x = f2bf(f.x); h.y = f2bf(f.y); h.z = f2bf(f.z); h.w = f2bf(f.w);
        ((ushort4*)xb)[i] = h;
    } else if (i < nx4 + 16384) {           // 4 matrices * 4096 float4
        int wi = i - nx4;
        int m = wi >> 12;
        const float* W = (m == 0) ? Wq : (m == 1) ? Wk : (m == 2) ? Wv : Ws;
        float4 f = ((const float4*)W)[wi & 4095];
        ushort4 h;
        h.x = f2bf(f.x); h.y = f2bf(f.y); h.z = f2bf(f.z); h.w = f2bf(f.w);
        ((ushort4*)wb)[wi] = h;
    } else if (i < nx4 + 16384 + N) {
        counts[i - nx4 - 16384] = 0;
    }
}

// ---------------------------------------------------------------------------
// MFMA projection GEMM. Block = 512 threads = 8 waves, 64 rows per block.
// Wave w: matrix = w>>1 (0=q,1=k,2=v,3=skip), cols (w&1)*64 .. +63.
// y = x @ W^T: A-frag = x rows (bf16x8 contiguous), B-frag = W rows.
// C layout: col=lane&15, row=(lane>>4)*4+reg.
// qkv layout [N][384] bf16: q at 0..127; k/v interleaved at 128..383 as
// (k[2d],k[2d+1],v[2d],v[2d+1]) per d=0..63  -> attn reads one uint2/lane.
// ---------------------------------------------------------------------------
__global__ __launch_bounds__(512) void mfma_qkvs(
    const ushort* __restrict__ xb, const ushort* __restrict__ wb,
    const float* __restrict__ bq, const float* __restrict__ bk,
    const float* __restrict__ bv, const float* __restrict__ bsk,
    const float* __restrict__ x,
    ushort* __restrict__ qkv, float* __restrict__ out, int N)
{
    __shared__ __align__(16) ushort stg[8][16][64];

    const int t = threadIdx.x;
    const int w = t >> 6, l = t & 63;
    const int mat = w >> 1;
    const int col0 = (w & 1) * 64;
    const int r0 = blockIdx.x * 64;
    const int lr = l & 15, lg = l >> 4;

    const ushort* W = wb + (size_t)mat * (D * D);
    const float* bias = (mat == 0) ? bq : (mat == 1) ? bk : (mat == 2) ? bv : bsk;

    float bi[4];
    #pragma unroll
    for (int ct = 0; ct < 4; ++ct) bi[ct] = bias[col0 + ct * 16 + lr];

    f32x4 acc[4][4];
    #pragma unroll
    for (int rt = 0; rt < 4; ++rt)
        #pragma unroll
        for (int ct = 0; ct < 4; ++ct)
            acc[rt][ct] = (f32x4){0.f, 0.f, 0.f, 0.f};

    int arow[4];
    #pragma unroll
    for (int rt = 0; rt < 4; ++rt) arow[rt] = min(r0 + rt * 16 + lr, N - 1);

    #pragma unroll
    for (int ks = 0; ks < 4; ++ks) {
        const int kofs = ks * 32 + lg * 8;
        short8 a[4], b[4];
        #pragma unroll
        for (int rt = 0; rt < 4; ++rt)
            a[rt] = *(const short8*)(xb + (size_t)arow[rt] * D + kofs);
        #pragma unroll
        for (int ct = 0; ct < 4; ++ct)
            b[ct] = *(const short8*)(W + (size_t)(col0 + ct * 16 + lr) * D + kofs);
        #pragma unroll
        for (int rt = 0; rt < 4; ++rt)
            #pragma unroll
            for (int ct = 0; ct < 4; ++ct)
                acc[rt][ct] = __builtin_amdgcn_mfma_f32_16x16x32_bf16(
                    a[rt], b[ct], acc[rt][ct], 0, 0, 0);
    }

    // Epilogue: 4 chunks of 16 rows; same-wave LDS write->read (in-order DS pipe).
    for (int rt = 0; rt < 4; ++rt) {
        #pragma unroll
        for (int ct = 0; ct < 4; ++ct) {
            const int colL = ct * 16 + lr;
            const int cch = colL >> 3, cin = colL & 7;
            #pragma unroll
            for (int r = 0; r < 4; ++r) {
                const int rowL = lg * 4 + r;
                stg[w][rowL][((cch ^ (rowL & 7)) << 3) + cin] =
                    f2bf(acc[rt][ct][r] + bi[ct]);
            }
        }
        #pragma unroll
        for (int rr = 0; rr < 2; ++rr) {
            const int rowL = rr * 8 + (l >> 3);
            const int c = l & 7;
            const int p = c ^ (rowL & 7);
            uint4 hv = *(const uint4*)&stg[w][rowL][p << 3];
            const int row_g = r0 + rt * 16 + rowL;
            if (row_g < N) {
                if (mat == 0) {
                    *(uint4*)(qkv + (size_t)row_g * 384 + col0 + c * 8) = hv;
                } else if (mat < 3) {
                    uint* du = (uint*)(qkv + (size_t)row_g * 384 + 128
                                       + 2 * col0 + 16 * c + ((mat == 2) ? 2 : 0));
                    const uint* hu = (const uint*)&hv;
                    #pragma unroll
                    for (int tt = 0; tt < 4; ++tt) du[tt * 2] = hu[tt];
                } else {
                    const ushort* hs = (const ushort*)&hv;
                    const float4* xr = (const float4*)(x + (size_t)row_g * D + col0 + c * 8);
                    float4 x0 = xr[0], x1 = xr[1];
                    float4 o0, o1;
                    o0.x = x0.x + bf2f(hs[0]); o0.y = x0.y + bf2f(hs[1]);
                    o0.z = x0.z + bf2f(hs[2]); o0.w = x0.w + bf2f(hs[3]);
                    o1.x = x1.x + bf2f(hs[4]); o1.y = x1.y + bf2f(hs[5]);
                    o1.z = x1.z + bf2f(hs[6]); o1.w = x1.w + bf2f(hs[7]);
                    float4* orow = (float4*)(out + (size_t)row_g * D + col0 + c * 8);
                    orow[0] = o0; orow[1] = o1;
                }
            }
        }
    }
}

// ---------------------------------------------------------------------------
// CSR build
// ---------------------------------------------------------------------------
__global__ void hist_kernel(const int* __restrict__ dst, int* __restrict__ counts, int E)
{
    int e = blockIdx.x * 256 + threadIdx.x;
    if (e < E) atomicAdd(&counts[dst[e]], 1);
}

__global__ __launch_bounds__(1024) void scan_blocks(
    const int* __restrict__ counts, int* __restrict__ offsets,
    int* __restrict__ partials, int n)
{
    __shared__ int sm[1024];
    int tid = threadIdx.x;
    int i = blockIdx.x * 1024 + tid;
    int v = (i < n) ? counts[i] : 0;
    sm[tid] = v;
    __syncthreads();
    for (int off = 1; off < 1024; off <<= 1) {
        int tv = (tid >= off) ? sm[tid - off] : 0;
        __syncthreads();
        sm[tid] += tv;
        __syncthreads();
    }
    if (i < n) offsets[i] = sm[tid] - v;
    if (tid == 1023) partials[blockIdx.x] = sm[1023];
}

__global__ void scan_partials(int* __restrict__ p, int nb)
{
    const int l = threadIdx.x;   // 64 threads
    int base = 0;
    for (int s = 0; s < nb; s += 64) {
        int idx = s + l;
        int v = (idx < nb) ? p[idx] : 0;
        const int orig = v;
        #pragma unroll
        for (int off = 1; off < 64; off <<= 1) {
            int tv = __shfl_up(v, off);
            if (l >= off) v += tv;
        }
        if (idx < nb) p[idx] = base + v - orig;   // exclusive
        base += __shfl(v, 63);
    }
}

__global__ __launch_bounds__(1024) void scan_add(
    int* __restrict__ offsets, int* __restrict__ cursor,
    const int* __restrict__ partials, int n)
{
    int i = blockIdx.x * 1024 + threadIdx.x;
    if (i < n) {
        int v = offsets[i] + partials[blockIdx.x];
        offsets[i] = v;
        cursor[i]  = v;
    }
}

__global__ void scatter_kernel(const int* __restrict__ src, const int* __restrict__ dst,
                               int* __restrict__ cursor, int* __restrict__ edge_src, int E)
{
    int e = blockIdx.x * 256 + threadIdx.x;
    if (e < E) {
        int p = atomicAdd(&cursor[dst[e]], 1);
        edge_src[p] = src[e];
    }
}

// ---------------------------------------------------------------------------
// Attention: one wave per destination node, lane owns dims 2*lane..2*lane+1,
// head = lane>>4. bf16 k/v interleaved -> one 8B load per edge per lane.
// FOUR independent online-softmax states per lane (edges round-robin by
// e&3) break the serial m/l/a dependency chain; states merged at the end.
// One-group-deep prefetch of indices + k/v overlaps gather latency.
// ---------------------------------------------------------------------------
__global__ __launch_bounds__(256) void attn_kernel(
    const ushort* __restrict__ qkv, const int* __restrict__ counts,
    const int* __restrict__ offsets, const int* __restrict__ edge_src,
    float* __restrict__ out, int N)
{
    const int lane = threadIdx.x & 63;
    const int wv   = threadIdx.x >> 6;
    const int i    = blockIdx.x * 4 + wv;
    if (i >= N) return;

    const float scale = 0.17677669529663687f;   // 1/sqrt(32)
    const uint qb = *(const uint*)(qkv + (size_t)i * 384 + 2 * lane);
    const float q0 = lo2f(qb) * scale, q1 = hi2f(qb) * scale;

    const int beg = offsets[i];
    const int cnt = counts[i];

    float m[4] = {-INFINITY, -INFINITY, -INFINITY, -INFINITY};
    float lsum[4] = {0.f, 0.f, 0.f, 0.f};
    float ax[4] = {0.f, 0.f, 0.f, 0.f};
    float ay[4] = {0.f, 0.f, 0.f, 0.f};

    if (cnt > 0) {
        const int cnt4 = cnt & ~3;
        uint2 kv[4];
        {
            int j[4];
            #pragma unroll
            for (int s = 0; s < 4; ++s) j[s] = edge_src[beg + min(s, cnt - 1)];
            #pragma unroll
            for (int s = 0; s < 4; ++s)
                kv[s] = *(const uint2*)(qkv + (size_t)j[s] * 384 + 128 + 4 * lane);
        }

        for (int e = 0; e < cnt4; e += 4) {
            // prefetch next group (clamped; tail values land in kv[])
            int jn[4];
            #pragma unroll
            for (int s = 0; s < 4; ++s)
                jn[s] = edge_src[beg + min(e + 4 + s, cnt - 1)];
            uint2 kvn[4];
            #pragma unroll
            for (int s = 0; s < 4; ++s)
                kvn[s] = *(const uint2*)(qkv + (size_t)jn[s] * 384 + 128 + 4 * lane);

            // 4 independent dot->softmax-update chains
            #pragma unroll
            for (int s = 0; s < 4; ++s) {
                float dot = q0 * lo2f(kv[s].x) + q1 * hi2f(kv[s].x);
                dot += __shfl_xor(dot, 1);
                dot += __shfl_xor(dot, 2);
                dot += __shfl_xor(dot, 4);
                dot += __shfl_xor(dot, 8);
                const float mn = fmaxf(m[s], dot);
                const float p  = __expf(dot - mn);
                const float sc = __expf(m[s] - mn);
                lsum[s] = lsum[s] * sc + p;
                ax[s]   = ax[s]   * sc + p * lo2f(kv[s].y);
                ay[s]   = ay[s]   * sc + p * hi2f(kv[s].y);
                m[s] = mn;
            }
            #pragma unroll
            for (int s = 0; s < 4; ++s) kv[s] = kvn[s];
        }

        // tail: edges cnt4..cnt-1 are in kv[0..cnt-cnt4-1]
        for (int e = cnt4; e < cnt; ++e) {
            const int s = e & 3;
            float dot = q0 * lo2f(kv[s].x) + q1 * hi2f(kv[s].x);
            dot += __shfl_xor(dot, 1);
            dot += __shfl_xor(dot, 2);
            dot += __shfl_xor(dot, 4);
            dot += __shfl_xor(dot, 8);
            const float mn = fmaxf(m[s], dot);
            const float p  = __expf(dot - mn);
            const float sc = __expf(m[s] - mn);
            lsum[s] = lsum[s] * sc + p;
            ax[s]   = ax[s]   * sc + p * lo2f(kv[s].y);
            ay[s]   = ay[s]   * sc + p * hi2f(kv[s].y);
            m[s] = mn;
        }

        // merge states 1..3 into 0 (state s nonempty iff cnt > s; uniform)
        #pragma unroll
        for (int s = 1; s < 4; ++s) {
            if (cnt > s) {
                const float M  = fmaxf(m[0], m[s]);
                const float s0 = __expf(m[0] - M);
                const float s1 = __expf(m[s] - M);
                lsum[0] = lsum[0] * s0 + lsum[s] * s1;
                ax[0]   = ax[0]   * s0 + ax[s]   * s1;
                ay[0]   = ay[0]   * s0 + ay[s]   * s1;
                m[0] = M;
            }
        }
    }

    const float inv = 1.0f / (lsum[0] + 1e-16f);
    float2* orow = (float2*)(out + (size_t)i * D);
    float2 b2 = orow[lane];
    b2.x += ax[0] * inv;
    b2.y += ay[0] * inv;
    orow[lane] = b2;
}

// ---------------------------------------------------------------------------
extern "C" void kernel_launch(void* const* d_in, const int* in_sizes, int n_in,
                              void* d_out, int out_size, void* d_ws, size_t ws_size,
                              hipStream_t stream)
{
    const float* x   = (const float*)d_in[0];
    const int*   ei  = (const int*)d_in[1];    // [2][E], row0=src, row1=dst
    const float* Wq  = (const float*)d_in[2];
    const float* bq  = (const float*)d_in[3];
    const float* Wk  = (const float*)d_in[4];
    const float* bk  = (const float*)d_in[5];
    const float* Wv  = (const float*)d_in[6];
    const float* bv  = (const float*)d_in[7];
    const float* Wsk = (const float*)d_in[8];
    const float* bsk = (const float*)d_in[9];
    float* out = (float*)d_out;

    const int N = in_sizes[0] / D;
    const int E = in_sizes[1] / 2;

    // workspace layout (~55 MB)
    char* ws = (char*)d_ws;
    size_t o = 0;
    ushort* xb      = (ushort*)(ws + o); o += (size_t)N * D * sizeof(ushort);
    ushort* wb      = (ushort*)(ws + o); o += (size_t)4 * D * D * sizeof(ushort);
    ushort* qkv     = (ushort*)(ws + o); o += (size_t)N * 384 * sizeof(ushort);
    o = (o + 255) & ~(size_t)255;
    int*   counts   = (int*)(ws + o);    o += (size_t)N * sizeof(int);
    int*   offsets  = (int*)(ws + o);    o += (size_t)N * sizeof(int);
    int*   cursor   = (int*)(ws + o);    o += (size_t)N * sizeof(int);
    int*   partials = (int*)(ws + o);    o += 4096;
    int*   edge_src = (int*)(ws + o);    o += (size_t)E * sizeof(int);

    const int nx4 = N * D / 4;
    const int conv_total = nx4 + 16384 + N;
    convert_kernel<<<(conv_total + 255) / 256, 256, 0, stream>>>(
        x, Wq, Wk, Wv, Wsk, xb, wb, counts, nx4, N);

    mfma_qkvs<<<(N + 63) / 64, 512, 0, stream>>>(
        xb, wb, bq, bk, bv, bsk, x, qkv, out, N);

    hist_kernel<<<(E + 255) / 256, 256, 0, stream>>>(ei + E, counts, E);

    int nb = (N + 1023) / 1024;
    scan_blocks<<<nb, 1024, 0, stream>>>(counts, offsets, partials, N);
    scan_partials<<<1, 64, 0, stream>>>(partials, nb);
    scan_add<<<nb, 1024, 0, stream>>>(offsets, cursor, partials, N);
    scatter_kernel<<<(E + 255) / 256, 256, 0, stream>>>(ei, ei + E, cursor, edge_src, E);

    attn_kernel<<<(N + 3) / 4, 256, 0, stream>>>(qkv, counts, offsets, edge_src, out, N);
}

// Round 5
// 228.608 us; speedup vs baseline: 1.1554x; 1.1554x over previous
//
#include <hip/hip_runtime.h>
#include <math.h>

#define D 128

typedef __attribute__((ext_vector_type(8))) short short8;
typedef __attribute__((ext_vector_type(4))) float f32x4;

__device__ __forceinline__ ushort f2bf(float f) {
    uint u = __float_as_uint(f);
    u += 0x7FFFu + ((u >> 16) & 1u);       // round-to-nearest-even
    return (ushort)(u >> 16);
}
__device__ __forceinline__ float bf2f(ushort h) { return __uint_as_float(((uint)h) << 16); }
__device__ __forceinline__ float lo2f(uint u) { return __uint_as_float(u << 16); }
__device__ __forceinline__ float hi2f(uint u) { return __uint_as_float(u & 0xFFFF0000u); }

// ---------------------------------------------------------------------------
// Convert x (N*128) and the 4 weight matrices (4*128*128) to bf16,
// and zero the counts array (fused, capture-safe).
// ---------------------------------------------------------------------------
__global__ void convert_kernel(
    const float* __restrict__ x,
    const float* __restrict__ Wq, const float* __restrict__ Wk,
    const float* __restrict__ Wv, const float* __restrict__ Ws,
    ushort* __restrict__ xb, ushort* __restrict__ wb,
    int* __restrict__ counts, int nx4, int N)
{
    int i = blockIdx.x * 256 + threadIdx.x;
    if (i < nx4) {
        float4 f = ((const float4*)x)[i];
        ushort4 h;
        h.x = f2bf(f.x); h.y = f2bf(f.y); h.z = f2bf(f.z); h.w = f2bf(f.w);
        ((ushort4*)xb)[i] = h;
    } else if (i < nx4 + 16384) {           // 4 matrices * 4096 float4
        int wi = i - nx4;
        int m = wi >> 12;
        const float* W = (m == 0) ? Wq : (m == 1) ? Wk : (m == 2) ? Wv : Ws;
        float4 f = ((const float4*)W)[wi & 4095];
        ushort4 h;
        h.x = f2bf(f.x); h.y = f2bf(f.y); h.z = f2bf(f.z); h.w = f2bf(f.w);
        ((ushort4*)wb)[wi] = h;
    } else if (i < nx4 + 16384 + N) {
        counts[i - nx4 - 16384] = 0;
    }
}

// ---------------------------------------------------------------------------
// MFMA projection GEMM. Block = 512 threads = 8 waves, 64 rows per block.
// Wave w: matrix = w>>1 (0=q,1=k,2=v,3=skip), cols (w&1)*64 .. +63.
// qkv layout [N][384] bf16: q at 0..127; k/v interleaved at 128..383 as
// (k[2d],k[2d+1],v[2d],v[2d+1]) per d=0..63  -> attn reads one uint2/lane.
// ---------------------------------------------------------------------------
__global__ __launch_bounds__(512) void mfma_qkvs(
    const ushort* __restrict__ xb, const ushort* __restrict__ wb,
    const float* __restrict__ bq, const float* __restrict__ bk,
    const float* __restrict__ bv, const float* __restrict__ bsk,
    const float* __restrict__ x,
    ushort* __restrict__ qkv, float* __restrict__ out, int N)
{
    __shared__ __align__(16) ushort stg[8][16][64];

    const int t = threadIdx.x;
    const int w = t >> 6, l = t & 63;
    const int mat = w >> 1;
    const int col0 = (w & 1) * 64;
    const int r0 = blockIdx.x * 64;
    const int lr = l & 15, lg = l >> 4;

    const ushort* W = wb + (size_t)mat * (D * D);
    const float* bias = (mat == 0) ? bq : (mat == 1) ? bk : (mat == 2) ? bv : bsk;

    float bi[4];
    #pragma unroll
    for (int ct = 0; ct < 4; ++ct) bi[ct] = bias[col0 + ct * 16 + lr];

    f32x4 acc[4][4];
    #pragma unroll
    for (int rt = 0; rt < 4; ++rt)
        #pragma unroll
        for (int ct = 0; ct < 4; ++ct)
            acc[rt][ct] = (f32x4){0.f, 0.f, 0.f, 0.f};

    int arow[4];
    #pragma unroll
    for (int rt = 0; rt < 4; ++rt) arow[rt] = min(r0 + rt * 16 + lr, N - 1);

    #pragma unroll
    for (int ks = 0; ks < 4; ++ks) {
        const int kofs = ks * 32 + lg * 8;
        short8 a[4], b[4];
        #pragma unroll
        for (int rt = 0; rt < 4; ++rt)
            a[rt] = *(const short8*)(xb + (size_t)arow[rt] * D + kofs);
        #pragma unroll
        for (int ct = 0; ct < 4; ++ct)
            b[ct] = *(const short8*)(W + (size_t)(col0 + ct * 16 + lr) * D + kofs);
        #pragma unroll
        for (int rt = 0; rt < 4; ++rt)
            #pragma unroll
            for (int ct = 0; ct < 4; ++ct)
                acc[rt][ct] = __builtin_amdgcn_mfma_f32_16x16x32_bf16(
                    a[rt], b[ct], acc[rt][ct], 0, 0, 0);
    }

    // Epilogue: 4 chunks of 16 rows; same-wave LDS write->read (in-order DS pipe).
    for (int rt = 0; rt < 4; ++rt) {
        #pragma unroll
        for (int ct = 0; ct < 4; ++ct) {
            const int colL = ct * 16 + lr;
            const int cch = colL >> 3, cin = colL & 7;
            #pragma unroll
            for (int r = 0; r < 4; ++r) {
                const int rowL = lg * 4 + r;
                stg[w][rowL][((cch ^ (rowL & 7)) << 3) + cin] =
                    f2bf(acc[rt][ct][r] + bi[ct]);
            }
        }
        #pragma unroll
        for (int rr = 0; rr < 2; ++rr) {
            const int rowL = rr * 8 + (l >> 3);
            const int c = l & 7;
            const int p = c ^ (rowL & 7);
            uint4 hv = *(const uint4*)&stg[w][rowL][p << 3];
            const int row_g = r0 + rt * 16 + rowL;
            if (row_g < N) {
                if (mat == 0) {
                    *(uint4*)(qkv + (size_t)row_g * 384 + col0 + c * 8) = hv;
                } else if (mat < 3) {
                    uint* du = (uint*)(qkv + (size_t)row_g * 384 + 128
                                       + 2 * col0 + 16 * c + ((mat == 2) ? 2 : 0));
                    const uint* hu = (const uint*)&hv;
                    #pragma unroll
                    for (int tt = 0; tt < 4; ++tt) du[tt * 2] = hu[tt];
                } else {
                    const ushort* hs = (const ushort*)&hv;
                    const float4* xr = (const float4*)(x + (size_t)row_g * D + col0 + c * 8);
                    float4 x0 = xr[0], x1 = xr[1];
                    float4 o0, o1;
                    o0.x = x0.x + bf2f(hs[0]); o0.y = x0.y + bf2f(hs[1]);
                    o0.z = x0.z + bf2f(hs[2]); o0.w = x0.w + bf2f(hs[3]);
                    o1.x = x1.x + bf2f(hs[4]); o1.y = x1.y + bf2f(hs[5]);
                    o1.z = x1.z + bf2f(hs[6]); o1.w = x1.w + bf2f(hs[7]);
                    float4* orow = (float4*)(out + (size_t)row_g * D + col0 + c * 8);
                    orow[0] = o0; orow[1] = o1;
                }
            }
        }
    }
}

// ---------------------------------------------------------------------------
// CSR build
// ---------------------------------------------------------------------------
__global__ void hist_kernel(const int* __restrict__ dst, int* __restrict__ counts, int E)
{
    int e = blockIdx.x * 256 + threadIdx.x;
    if (e < E) atomicAdd(&counts[dst[e]], 1);
}

__global__ __launch_bounds__(1024) void scan_blocks(
    const int* __restrict__ counts, int* __restrict__ offsets,
    int* __restrict__ partials, int n)
{
    __shared__ int sm[1024];
    int tid = threadIdx.x;
    int i = blockIdx.x * 1024 + tid;
    int v = (i < n) ? counts[i] : 0;
    sm[tid] = v;
    __syncthreads();
    for (int off = 1; off < 1024; off <<= 1) {
        int tv = (tid >= off) ? sm[tid - off] : 0;
        __syncthreads();
        sm[tid] += tv;
        __syncthreads();
    }
    if (i < n) offsets[i] = sm[tid] - v;
    if (tid == 1023) partials[blockIdx.x] = sm[1023];
}

__global__ void scan_partials(int* __restrict__ p, int nb)
{
    const int l = threadIdx.x;   // 64 threads
    int base = 0;
    for (int s = 0; s < nb; s += 64) {
        int idx = s + l;
        int v = (idx < nb) ? p[idx] : 0;
        const int orig = v;
        #pragma unroll
        for (int off = 1; off < 64; off <<= 1) {
            int tv = __shfl_up(v, off);
            if (l >= off) v += tv;
        }
        if (idx < nb) p[idx] = base + v - orig;   // exclusive
        base += __shfl(v, 63);
    }
}

__global__ __launch_bounds__(1024) void scan_add(
    int* __restrict__ offsets, int* __restrict__ cursor,
    const int* __restrict__ partials, int n)
{
    int i = blockIdx.x * 1024 + threadIdx.x;
    if (i < n) {
        int v = offsets[i] + partials[blockIdx.x];
        offsets[i] = v;
        cursor[i]  = v;
    }
}

__global__ void scatter_kernel(const int* __restrict__ src, const int* __restrict__ dst,
                               int* __restrict__ cursor, int* __restrict__ edge_src, int E)
{
    int e = blockIdx.x * 256 + threadIdx.x;
    if (e < E) {
        int p = atomicAdd(&cursor[dst[e]], 1);
        edge_src[p] = src[e];
    }
}

// ---------------------------------------------------------------------------
// Attention: one wave per destination node, lane owns dims 2*lane..2*lane+1,
// head = lane>>4. bf16 k/v interleaved -> one 8B load per edge per lane.
// FOUR independent online-softmax chains (positions e%4 -> state e%4) break
// the serial m/l/a dependency; merged at the end. Loop is padded to a
// multiple of 4 with clamped indices + dot=-1e30 masking so EVERY array
// index is compile-time constant (rule #20: no scratch/LDS demotion).
// ---------------------------------------------------------------------------
__global__ __launch_bounds__(256) void attn_kernel(
    const ushort* __restrict__ qkv, const int* __restrict__ counts,
    const int* __restrict__ offsets, const int* __restrict__ edge_src,
    float* __restrict__ out, int N)
{
    const int lane = threadIdx.x & 63;
    const int wv   = threadIdx.x >> 6;
    const int i    = blockIdx.x * 4 + wv;
    if (i >= N) return;

    const float scale = 0.17677669529663687f;   // 1/sqrt(32)
    const uint qb = *(const uint*)(qkv + (size_t)i * 384 + 2 * lane);
    const float q0 = lo2f(qb) * scale, q1 = hi2f(qb) * scale;

    const int beg = offsets[i];
    const int cnt = counts[i];

    float m[4]    = {-INFINITY, -INFINITY, -INFINITY, -INFINITY};
    float lsum[4] = {0.f, 0.f, 0.f, 0.f};
    float ax[4]   = {0.f, 0.f, 0.f, 0.f};
    float ay[4]   = {0.f, 0.f, 0.f, 0.f};

    if (cnt > 0) {
        const int cnt_pad = (cnt + 3) & ~3;
        const int last = beg + cnt - 1;

        uint2 kv[4];
        #pragma unroll
        for (int s = 0; s < 4; ++s) {
            const int j = edge_src[min(beg + s, last)];
            kv[s] = *(const uint2*)(qkv + (size_t)j * 384 + 128 + 4 * lane);
        }

        for (int e = 0; e < cnt_pad; e += 4) {
            // prefetch next group (clamped)
            uint2 kvn[4];
            #pragma unroll
            for (int s = 0; s < 4; ++s) {
                const int j = edge_src[min(beg + e + 4 + s, last)];
                kvn[s] = *(const uint2*)(qkv + (size_t)j * 384 + 128 + 4 * lane);
            }

            #pragma unroll
            for (int s = 0; s < 4; ++s) {
                float dot = q0 * lo2f(kv[s].x) + q1 * hi2f(kv[s].x);
                dot += __shfl_xor(dot, 1);
                dot += __shfl_xor(dot, 2);
                dot += __shfl_xor(dot, 4);
                dot += __shfl_xor(dot, 8);
                if (e + s >= cnt) dot = -1e30f;      // masked pad slot
                const float mn = fmaxf(m[s], dot);
                const float p  = __expf(dot - mn);
                const float sc = __expf(m[s] - mn);
                lsum[s] = lsum[s] * sc + p;
                ax[s]   = ax[s]   * sc + p * lo2f(kv[s].y);
                ay[s]   = ay[s]   * sc + p * hi2f(kv[s].y);
                m[s] = mn;
            }
            #pragma unroll
            for (int s = 0; s < 4; ++s) kv[s] = kvn[s];
        }

        // merge states 1..3 into 0 (state s valid iff cnt > s; wave-uniform)
        #pragma unroll
        for (int s = 1; s < 4; ++s) {
            if (cnt > s) {
                const float M  = fmaxf(m[0], m[s]);
                const float s0 = __expf(m[0] - M);
                const float s1 = __expf(m[s] - M);
                lsum[0] = lsum[0] * s0 + lsum[s] * s1;
                ax[0]   = ax[0]   * s0 + ax[s]   * s1;
                ay[0]   = ay[0]   * s0 + ay[s]   * s1;
                m[0] = M;
            }
        }
    }

    const float inv = 1.0f / (lsum[0] + 1e-16f);
    float2* orow = (float2*)(out + (size_t)i * D);
    float2 b2 = orow[lane];
    b2.x += ax[0] * inv;
    b2.y += ay[0] * inv;
    orow[lane] = b2;
}

// ---------------------------------------------------------------------------
extern "C" void kernel_launch(void* const* d_in, const int* in_sizes, int n_in,
                              void* d_out, int out_size, void* d_ws, size_t ws_size,
                              hipStream_t stream)
{
    const float* x   = (const float*)d_in[0];
    const int*   ei  = (const int*)d_in[1];    // [2][E], row0=src, row1=dst
    const float* Wq  = (const float*)d_in[2];
    const float* bq  = (const float*)d_in[3];
    const float* Wk  = (const float*)d_in[4];
    const float* bk  = (const float*)d_in[5];
    const float* Wv  = (const float*)d_in[6];
    const float* bv  = (const float*)d_in[7];
    const float* Wsk = (const float*)d_in[8];
    const float* bsk = (const float*)d_in[9];
    float* out = (float*)d_out;

    const int N = in_sizes[0] / D;
    const int E = in_sizes[1] / 2;

    // workspace layout (~55 MB)
    char* ws = (char*)d_ws;
    size_t o = 0;
    ushort* xb      = (ushort*)(ws + o); o += (size_t)N * D * sizeof(ushort);
    ushort* wb      = (ushort*)(ws + o); o += (size_t)4 * D * D * sizeof(ushort);
    ushort* qkv     = (ushort*)(ws + o); o += (size_t)N * 384 * sizeof(ushort);
    o = (o + 255) & ~(size_t)255;
    int*   counts   = (int*)(ws + o);    o += (size_t)N * sizeof(int);
    int*   offsets  = (int*)(ws + o);    o += (size_t)N * sizeof(int);
    int*   cursor   = (int*)(ws + o);    o += (size_t)N * sizeof(int);
    int*   partials = (int*)(ws + o);    o += 4096;
    int*   edge_src = (int*)(ws + o);    o += (size_t)E * sizeof(int);

    const int nx4 = N * D / 4;
    const int conv_total = nx4 + 16384 + N;
    convert_kernel<<<(conv_total + 255) / 256, 256, 0, stream>>>(
        x, Wq, Wk, Wv, Wsk, xb, wb, counts, nx4, N);

    mfma_qkvs<<<(N + 63) / 64, 512, 0, stream>>>(
        xb, wb, bq, bk, bv, bsk, x, qkv, out, N);

    hist_kernel<<<(E + 255) / 256, 256, 0, stream>>>(ei + E, counts, E);

    int nb = (N + 1023) / 1024;
    scan_blocks<<<nb, 1024, 0, stream>>>(counts, offsets, partials, N);
    scan_partials<<<1, 64, 0, stream>>>(partials, nb);
    scan_add<<<nb, 1024, 0, stream>>>(offsets, cursor, partials, N);
    scatter_kernel<<<(E + 255) / 256, 256, 0, stream>>>(ei, ei + E, cursor, edge_src, E);

    attn_kernel<<<(N + 3) / 4, 256, 0, stream>>>(qkv, counts, offsets, edge_src, out, N);
}

// Round 6
// 218.305 us; speedup vs baseline: 1.2099x; 1.0472x over previous
//
#include <hip/hip_runtime.h>
#include <math.h>

#define D 128

typedef __attribute__((ext_vector_type(8))) short short8;
typedef __attribute__((ext_vector_type(4))) float f32x4;

__device__ __forceinline__ ushort f2bf(float f) {
    uint u = __float_as_uint(f);
    u += 0x7FFFu + ((u >> 16) & 1u);       // round-to-nearest-even
    return (ushort)(u >> 16);
}
__device__ __forceinline__ float bf2f(ushort h) { return __uint_as_float(((uint)h) << 16); }
__device__ __forceinline__ float lo2f(uint u) { return __uint_as_float(u << 16); }
__device__ __forceinline__ float hi2f(uint u) { return __uint_as_float(u & 0xFFFF0000u); }

// ---------------------------------------------------------------------------
// Convert x (N*128) and the 4 weight matrices (4*128*128) to bf16,
// and zero the counts array (fused, capture-safe).
// ---------------------------------------------------------------------------
__global__ void convert_kernel(
    const float* __restrict__ x,
    const float* __restrict__ Wq, const float* __restrict__ Wk,
    const float* __restrict__ Wv, const float* __restrict__ Ws,
    ushort* __restrict__ xb, ushort* __restrict__ wb,
    int* __restrict__ counts, int nx4, int N)
{
    int i = blockIdx.x * 256 + threadIdx.x;
    if (i < nx4) {
        float4 f = ((const float4*)x)[i];
        ushort4 h;
        h.x = f2bf(f.x); h.y = f2bf(f.y); h.z = f2bf(f.z); h.w = f2bf(f.w);
        ((ushort4*)xb)[i] = h;
    } else if (i < nx4 + 16384) {           // 4 matrices * 4096 float4
        int wi = i - nx4;
        int m = wi >> 12;
        const float* W = (m == 0) ? Wq : (m == 1) ? Wk : (m == 2) ? Wv : Ws;
        float4 f = ((const float4*)W)[wi & 4095];
        ushort4 h;
        h.x = f2bf(f.x); h.y = f2bf(f.y); h.z = f2bf(f.z); h.w = f2bf(f.w);
        ((ushort4*)wb)[wi] = h;
    } else if (i < nx4 + 16384 + N) {
        counts[i - nx4 - 16384] = 0;
    }
}

// ---------------------------------------------------------------------------
// MFMA projection GEMM. Block = 512 threads = 8 waves, 64 rows per block.
// Wave w: matrix = w>>1 (0=q,1=k,2=v,3=skip), cols (w&1)*64 .. +63.
// qkv layout [N][384] bf16: q at 0..127; k/v interleaved at 128..383 as
// (k[2d],k[2d+1],v[2d],v[2d+1]) per d=0..63.
// ---------------------------------------------------------------------------
__global__ __launch_bounds__(512) void mfma_qkvs(
    const ushort* __restrict__ xb, const ushort* __restrict__ wb,
    const float* __restrict__ bq, const float* __restrict__ bk,
    const float* __restrict__ bv, const float* __restrict__ bsk,
    const float* __restrict__ x,
    ushort* __restrict__ qkv, float* __restrict__ out, int N)
{
    __shared__ __align__(16) ushort stg[8][16][64];

    const int t = threadIdx.x;
    const int w = t >> 6, l = t & 63;
    const int mat = w >> 1;
    const int col0 = (w & 1) * 64;
    const int r0 = blockIdx.x * 64;
    const int lr = l & 15, lg = l >> 4;

    const ushort* W = wb + (size_t)mat * (D * D);
    const float* bias = (mat == 0) ? bq : (mat == 1) ? bk : (mat == 2) ? bv : bsk;

    float bi[4];
    #pragma unroll
    for (int ct = 0; ct < 4; ++ct) bi[ct] = bias[col0 + ct * 16 + lr];

    f32x4 acc[4][4];
    #pragma unroll
    for (int rt = 0; rt < 4; ++rt)
        #pragma unroll
        for (int ct = 0; ct < 4; ++ct)
            acc[rt][ct] = (f32x4){0.f, 0.f, 0.f, 0.f};

    int arow[4];
    #pragma unroll
    for (int rt = 0; rt < 4; ++rt) arow[rt] = min(r0 + rt * 16 + lr, N - 1);

    #pragma unroll
    for (int ks = 0; ks < 4; ++ks) {
        const int kofs = ks * 32 + lg * 8;
        short8 a[4], b[4];
        #pragma unroll
        for (int rt = 0; rt < 4; ++rt)
            a[rt] = *(const short8*)(xb + (size_t)arow[rt] * D + kofs);
        #pragma unroll
        for (int ct = 0; ct < 4; ++ct)
            b[ct] = *(const short8*)(W + (size_t)(col0 + ct * 16 + lr) * D + kofs);
        #pragma unroll
        for (int rt = 0; rt < 4; ++rt)
            #pragma unroll
            for (int ct = 0; ct < 4; ++ct)
                acc[rt][ct] = __builtin_amdgcn_mfma_f32_16x16x32_bf16(
                    a[rt], b[ct], acc[rt][ct], 0, 0, 0);
    }

    // Epilogue: 4 chunks of 16 rows; same-wave LDS write->read.
    for (int rt = 0; rt < 4; ++rt) {
        #pragma unroll
        for (int ct = 0; ct < 4; ++ct) {
            const int colL = ct * 16 + lr;
            const int cch = colL >> 3, cin = colL & 7;
            #pragma unroll
            for (int r = 0; r < 4; ++r) {
                const int rowL = lg * 4 + r;
                stg[w][rowL][((cch ^ (rowL & 7)) << 3) + cin] =
                    f2bf(acc[rt][ct][r] + bi[ct]);
            }
        }
        #pragma unroll
        for (int rr = 0; rr < 2; ++rr) {
            const int rowL = rr * 8 + (l >> 3);
            const int c = l & 7;
            const int p = c ^ (rowL & 7);
            uint4 hv = *(const uint4*)&stg[w][rowL][p << 3];
            const int row_g = r0 + rt * 16 + rowL;
            if (row_g < N) {
                if (mat == 0) {
                    *(uint4*)(qkv + (size_t)row_g * 384 + col0 + c * 8) = hv;
                } else if (mat < 3) {
                    uint* du = (uint*)(qkv + (size_t)row_g * 384 + 128
                                       + 2 * col0 + 16 * c + ((mat == 2) ? 2 : 0));
                    const uint* hu = (const uint*)&hv;
                    #pragma unroll
                    for (int tt = 0; tt < 4; ++tt) du[tt * 2] = hu[tt];
                } else {
                    const ushort* hs = (const ushort*)&hv;
                    const float4* xr = (const float4*)(x + (size_t)row_g * D + col0 + c * 8);
                    float4 x0 = xr[0], x1 = xr[1];
                    float4 o0, o1;
                    o0.x = x0.x + bf2f(hs[0]); o0.y = x0.y + bf2f(hs[1]);
                    o0.z = x0.z + bf2f(hs[2]); o0.w = x0.w + bf2f(hs[3]);
                    o1.x = x1.x + bf2f(hs[4]); o1.y = x1.y + bf2f(hs[5]);
                    o1.z = x1.z + bf2f(hs[6]); o1.w = x1.w + bf2f(hs[7]);
                    float4* orow = (float4*)(out + (size_t)row_g * D + col0 + c * 8);
                    orow[0] = o0; orow[1] = o1;
                }
            }
        }
    }
}

// ---------------------------------------------------------------------------
// CSR build
// ---------------------------------------------------------------------------
__global__ void hist_kernel(const int* __restrict__ dst, int* __restrict__ counts, int E)
{
    int e = blockIdx.x * 256 + threadIdx.x;
    if (e < E) atomicAdd(&counts[dst[e]], 1);
}

__global__ __launch_bounds__(1024) void scan_blocks(
    const int* __restrict__ counts, int* __restrict__ offsets,
    int* __restrict__ partials, int n)
{
    __shared__ int sm[1024];
    int tid = threadIdx.x;
    int i = blockIdx.x * 1024 + tid;
    int v = (i < n) ? counts[i] : 0;
    sm[tid] = v;
    __syncthreads();
    for (int off = 1; off < 1024; off <<= 1) {
        int tv = (tid >= off) ? sm[tid - off] : 0;
        __syncthreads();
        sm[tid] += tv;
        __syncthreads();
    }
    if (i < n) offsets[i] = sm[tid] - v;
    if (tid == 1023) partials[blockIdx.x] = sm[1023];
}

// scan_add with inline partial-prefix (sums partials[0..bid-1]; nb <= 64*k small)
__global__ __launch_bounds__(1024) void scan_add(
    int* __restrict__ offsets, int* __restrict__ cursor,
    const int* __restrict__ partials, int n)
{
    __shared__ int base_sm;
    if (threadIdx.x < 64) {
        int v = 0;
        for (int j = threadIdx.x; j < (int)blockIdx.x; j += 64) v += partials[j];
        #pragma unroll
        for (int off = 32; off; off >>= 1) v += __shfl_down(v, off);
        if (threadIdx.x == 0) base_sm = v;
    }
    __syncthreads();
    int i = blockIdx.x * 1024 + threadIdx.x;
    if (i < n) {
        int v = offsets[i] + base_sm;
        offsets[i] = v;
        cursor[i]  = v;
    }
}

__global__ void scatter_kernel(const int* __restrict__ src, const int* __restrict__ dst,
                               int* __restrict__ cursor, int* __restrict__ edge_src, int E)
{
    int e = blockIdx.x * 256 + threadIdx.x;
    if (e < E) {
        int p = atomicAdd(&cursor[dst[e]], 1);
        edge_src[p] = src[e];
    }
}

// ---------------------------------------------------------------------------
// Attention: one wave per destination node, FOUR edges in flight per wave:
// slot = lane>>4 owns edge (e + slot); ld = lane&15 owns feature dims
// 8*ld..8*ld+7 (head = ld>>2; 8 dims never cross a 32-dim head boundary).
// Per edge-lane: two uint4 loads (interleaved k/v), 8-elem dot partial,
// 2-shuffle reduce within the 4-lane head group, online softmax per slot,
// p*v accumulate into av[8]. Cross-slot merge (xor 16,32) once at the end,
// guarded so empty/sentinel slots contribute weight 0. All register arrays
// statically indexed (rule #20).
// ---------------------------------------------------------------------------
__global__ __launch_bounds__(256) void attn_kernel(
    const ushort* __restrict__ qkv, const int* __restrict__ counts,
    const int* __restrict__ offsets, const int* __restrict__ edge_src,
    float* __restrict__ out, int N)
{
    const int lane = threadIdx.x & 63;
    const int slot = lane >> 4;
    const int ld   = lane & 15;
    const int wv   = threadIdx.x >> 6;
    const int i    = blockIdx.x * 4 + wv;
    if (i >= N) return;

    const float scale = 0.17677669529663687f;   // 1/sqrt(32)
    const uint4 qa = *(const uint4*)(qkv + (size_t)i * 384 + 8 * ld);
    float qf[8];
    qf[0] = lo2f(qa.x) * scale; qf[1] = hi2f(qa.x) * scale;
    qf[2] = lo2f(qa.y) * scale; qf[3] = hi2f(qa.y) * scale;
    qf[4] = lo2f(qa.z) * scale; qf[5] = hi2f(qa.z) * scale;
    qf[6] = lo2f(qa.w) * scale; qf[7] = hi2f(qa.w) * scale;

    const int beg = offsets[i];
    const int cnt = counts[i];

    float m = -INFINITY, l = 0.f;
    float av[8] = {0.f, 0.f, 0.f, 0.f, 0.f, 0.f, 0.f, 0.f};

    if (cnt > 0) {
        const int last = beg + cnt - 1;
        const ushort* kvb = qkv + 128 + 16 * ld;   // + j*384

        uint4 kA, kB;
        {
            const int j = edge_src[min(beg + slot, last)];
            const ushort* p = kvb + (size_t)j * 384;
            kA = *(const uint4*)p;
            kB = *(const uint4*)(p + 8);
        }

        for (int e = 0; e < cnt; e += 4) {
            // prefetch next group's k/v (clamped)
            uint4 nA, nB;
            {
                const int j = edge_src[min(beg + e + 4 + slot, last)];
                const ushort* p = kvb + (size_t)j * 384;
                nA = *(const uint4*)p;
                nB = *(const uint4*)(p + 8);
            }

            // kA: w0=k(d0,d1) w1=v(d0,d1) w2=k(d2,d3) w3=v(d2,d3); kB: dims +4..+7
            float dp;
            dp  = qf[0] * lo2f(kA.x) + qf[1] * hi2f(kA.x);
            dp += qf[2] * lo2f(kA.z) + qf[3] * hi2f(kA.z);
            dp += qf[4] * lo2f(kB.x) + qf[5] * hi2f(kB.x);
            dp += qf[6] * lo2f(kB.z) + qf[7] * hi2f(kB.z);
            dp += __shfl_xor(dp, 1);
            dp += __shfl_xor(dp, 2);
            if (e + slot >= cnt) dp = -1e30f;      // masked pad slot

            const float mn = fmaxf(m, dp);
            const float p  = __expf(dp - mn);
            const float sc = __expf(m - mn);
            l = l * sc + p;
            av[0] = av[0] * sc + p * lo2f(kA.y);
            av[1] = av[1] * sc + p * hi2f(kA.y);
            av[2] = av[2] * sc + p * lo2f(kA.w);
            av[3] = av[3] * sc + p * hi2f(kA.w);
            av[4] = av[4] * sc + p * lo2f(kB.y);
            av[5] = av[5] * sc + p * hi2f(kB.y);
            av[6] = av[6] * sc + p * lo2f(kB.w);
            av[7] = av[7] * sc + p * hi2f(kB.w);
            m = mn;
            kA = nA; kB = nB;
        }
    }

    // merge the 4 slot-states (xor 16, then 32); empty slots (m sentinel or
    // -inf) get weight 0 whenever any real state is present.
    #pragma unroll
    for (int dist = 16; dist <= 32; dist <<= 1) {
        const float mo = __shfl_xor(m, dist);
        const float lo_ = __shfl_xor(l, dist);
        float avo[8];
        #pragma unroll
        for (int d = 0; d < 8; ++d) avo[d] = __shfl_xor(av[d], dist);
        const float M  = fmaxf(m, mo);
        const float s0 = (m  > -INFINITY) ? __expf(m  - M) : 0.f;
        const float s1 = (mo > -INFINITY) ? __expf(mo - M) : 0.f;
        l = l * s0 + lo_ * s1;
        #pragma unroll
        for (int d = 0; d < 8; ++d) av[d] = av[d] * s0 + avo[d] * s1;
        m = M;
    }

    if (slot == 0) {
        const float inv = 1.0f / (l + 1e-16f);
        float4* orow = (float4*)(out + (size_t)i * D + 8 * ld);
        float4 o0 = orow[0], o1 = orow[1];
        o0.x += av[0] * inv; o0.y += av[1] * inv;
        o0.z += av[2] * inv; o0.w += av[3] * inv;
        o1.x += av[4] * inv; o1.y += av[5] * inv;
        o1.z += av[6] * inv; o1.w += av[7] * inv;
        orow[0] = o0; orow[1] = o1;
    }
}

// ---------------------------------------------------------------------------
extern "C" void kernel_launch(void* const* d_in, const int* in_sizes, int n_in,
                              void* d_out, int out_size, void* d_ws, size_t ws_size,
                              hipStream_t stream)
{
    const float* x   = (const float*)d_in[0];
    const int*   ei  = (const int*)d_in[1];    // [2][E], row0=src, row1=dst
    const float* Wq  = (const float*)d_in[2];
    const float* bq  = (const float*)d_in[3];
    const float* Wk  = (const float*)d_in[4];
    const float* bk  = (const float*)d_in[5];
    const float* Wv  = (const float*)d_in[6];
    const float* bv  = (const float*)d_in[7];
    const float* Wsk = (const float*)d_in[8];
    const float* bsk = (const float*)d_in[9];
    float* out = (float*)d_out;

    const int N = in_sizes[0] / D;
    const int E = in_sizes[1] / 2;

    // workspace layout (~55 MB)
    char* ws = (char*)d_ws;
    size_t o = 0;
    ushort* xb      = (ushort*)(ws + o); o += (size_t)N * D * sizeof(ushort);
    ushort* wb      = (ushort*)(ws + o); o += (size_t)4 * D * D * sizeof(ushort);
    ushort* qkv     = (ushort*)(ws + o); o += (size_t)N * 384 * sizeof(ushort);
    o = (o + 255) & ~(size_t)255;
    int*   counts   = (int*)(ws + o);    o += (size_t)N * sizeof(int);
    int*   offsets  = (int*)(ws + o);    o += (size_t)N * sizeof(int);
    int*   cursor   = (int*)(ws + o);    o += (size_t)N * sizeof(int);
    int*   partials = (int*)(ws + o);    o += 4096;
    int*   edge_src = (int*)(ws + o);    o += (size_t)E * sizeof(int);

    const int nx4 = N * D / 4;
    const int conv_total = nx4 + 16384 + N;
    convert_kernel<<<(conv_total + 255) / 256, 256, 0, stream>>>(
        x, Wq, Wk, Wv, Wsk, xb, wb, counts, nx4, N);

    mfma_qkvs<<<(N + 63) / 64, 512, 0, stream>>>(
        xb, wb, bq, bk, bv, bsk, x, qkv, out, N);

    hist_kernel<<<(E + 255) / 256, 256, 0, stream>>>(ei + E, counts, E);

    int nb = (N + 1023) / 1024;
    scan_blocks<<<nb, 1024, 0, stream>>>(counts, offsets, partials, N);
    scan_add<<<nb, 1024, 0, stream>>>(offsets, cursor, partials, N);
    scatter_kernel<<<(E + 255) / 256, 256, 0, stream>>>(ei, ei + E, cursor, edge_src, E);

    attn_kernel<<<(N + 3) / 4, 256, 0, stream>>>(qkv, counts, offsets, edge_src, out, N);
}